// Round 14
// baseline (84.217 us; speedup 1.0000x reference)
//
#include <hip/hip_runtime.h>
#include <hip/hip_bf16.h>

typedef _Float16 half_t;
typedef half_t halfx8 __attribute__((ext_vector_type(8)));
typedef half_t halfx4 __attribute__((ext_vector_type(4)));
typedef half_t halfx2 __attribute__((ext_vector_type(2)));
typedef __fp16 fp16x2 __attribute__((ext_vector_type(2)));
typedef float f32x4 __attribute__((ext_vector_type(4)));
typedef float f32x16 __attribute__((ext_vector_type(16)));
typedef int i32x4 __attribute__((ext_vector_type(4)));

#define B_ 8
#define C_ 128
#define T_ 4096
#define H_ 64
#define L2E 1.44269504088896340736f

static __device__ __forceinline__ halfx2 pk2(float a, float b) {
    fp16x2 r = __builtin_amdgcn_cvt_pkrtz(a, b);
    return __builtin_bit_cast(halfx2, r);
}
static __device__ __forceinline__ int pk2i(float a, float b) {
    return __builtin_bit_cast(int, __builtin_amdgcn_cvt_pkrtz(a, b));
}
// bare v_exp_f32 (exp2): avoids the ~6-instr __ocml_exp2_f32 denormal wrapper.
static __device__ __forceinline__ float fast_exp2(float x) {
    return __builtin_amdgcn_exp2f(x);
}
static __device__ __forceinline__ float max3f(float a, float b, float c) {
    return fmaxf(fmaxf(a, b), c);   // clang fuses to v_max3_f32
}
// XOR-swizzle for 64-col (128B-row) LDS tiles; col multiple of 8
static __device__ __forceinline__ int swz(int row, int col) {
    return (row << 6) + (col ^ ((row & 7) << 3));
}
// same swizzle, col multiple of 4 (quad-granular writes)
static __device__ __forceinline__ int swz4(int row, int col) {
    return (row << 6) + ((col & ~7) ^ ((row & 7) << 3)) + (col & 7);
}

// ---------------------------------------------------------------------------
// Kernel 1: projections. theta/phi/g = W[64,128] @ x[b][128, t-tile(64)] + bias
// Q (theta, pre-scaled by log2e) [B,T,H], K (phi) [B,T,H], Vt (g) [B,H,T], f16
// ---------------------------------------------------------------------------
__global__ __launch_bounds__(256) void proj_kernel(
    const float* __restrict__ x,
    const float* __restrict__ w_theta, const float* __restrict__ b_theta,
    const float* __restrict__ w_phi,   const float* __restrict__ b_phi,
    const float* __restrict__ w_g,     const float* __restrict__ b_g,
    half_t* __restrict__ Q, half_t* __restrict__ Ko, half_t* __restrict__ Vt)
{
    __shared__ __align__(16) half_t xt[64][136];   // [t][c]
    __shared__ __align__(16) half_t ts[64][72];    // transpose buf [t][h]

    const int tid  = threadIdx.x;
    const int lane = tid & 63;
    const int wave = tid >> 6;
    const int b    = blockIdx.x >> 6;
    const int t0   = (blockIdx.x & 63) << 6;

    const int rowA  = lane & 15;
    const int kgrp  = lane >> 4;
    const int row_d = kgrp << 2;

    const float* xb = x + (size_t)b * C_ * T_ + t0;
    #pragma unroll
    for (int it = 0; it < 8; ++it) {
        int li = it * 256 + tid;
        int c  = li >> 4;
        int tc = li & 15;
        f32x4 v = *(const f32x4*)(xb + (size_t)c * T_ + tc * 4);
        #pragma unroll
        for (int j = 0; j < 4; ++j) xt[tc * 4 + j][c] = (half_t)v[j];
    }

    const int h0 = wave << 4;
    const float* Ws[3] = {w_theta, w_phi, w_g};
    const float* Bs[3] = {b_theta, b_phi, b_g};
    halfx8 wa[3][4];
    #pragma unroll
    for (int m = 0; m < 3; ++m) {
        const float* wrow = Ws[m] + (size_t)(h0 + rowA) * C_;
        #pragma unroll
        for (int cc = 0; cc < 4; ++cc) {
            const float* p = wrow + cc * 32 + kgrp * 8;
            f32x4 a = *(const f32x4*)p;
            f32x4 c2 = *(const f32x4*)(p + 4);
            halfx8 f;
            f[0]=(half_t)a[0]; f[1]=(half_t)a[1]; f[2]=(half_t)a[2]; f[3]=(half_t)a[3];
            f[4]=(half_t)c2[0];f[5]=(half_t)c2[1];f[6]=(half_t)c2[2];f[7]=(half_t)c2[3];
            wa[m][cc] = f;
        }
    }

    __syncthreads();

    #pragma unroll
    for (int m = 0; m < 3; ++m) {
        f32x4 acc[4] = {};
        #pragma unroll
        for (int tt = 0; tt < 4; ++tt) {
            #pragma unroll
            for (int cc = 0; cc < 4; ++cc) {
                halfx8 bfrag = *(const halfx8*)&xt[tt * 16 + rowA][cc * 32 + kgrp * 8];
                acc[tt] = __builtin_amdgcn_mfma_f32_16x16x32_f16(wa[m][cc], bfrag, acc[tt], 0, 0, 0);
            }
        }
        float bias[4];
        #pragma unroll
        for (int r = 0; r < 4; ++r) bias[r] = Bs[m][h0 + row_d + r];

        if (m < 2) {
            const float sc = (m == 0) ? L2E : 1.0f;   // fold log2e into theta
            #pragma unroll
            for (int tt = 0; tt < 4; ++tt)
                #pragma unroll
                for (int r = 0; r < 4; ++r)
                    ts[tt * 16 + rowA][h0 + row_d + r] = (half_t)((acc[tt][r] + bias[r]) * sc);
            __syncthreads();
            half_t* dst = (m == 0 ? Q : Ko) + ((size_t)b * T_ + t0) * H_;
            #pragma unroll
            for (int it = 0; it < 2; ++it) {
                int q = it * 256 + tid;
                int t = q >> 3, hc = q & 7;
                *(halfx8*)(dst + (size_t)t * H_ + hc * 8) = *(const halfx8*)&ts[t][hc * 8];
            }
            __syncthreads();
        } else {
            half_t* dst = Vt + (size_t)b * H_ * T_ + t0;
            #pragma unroll
            for (int tt = 0; tt < 4; ++tt)
                #pragma unroll
                for (int r = 0; r < 4; ++r)
                    dst[(size_t)(h0 + row_d + r) * T_ + tt * 16 + rowA] = (half_t)(acc[tt][r] + bias[r]);
        }
    }
}

// ---------------------------------------------------------------------------
// Kernel 2: flash attention, 32x32 MFMA swapped-operand + KV-split (NS=4).
// K+V in XOR-swizzled LDS (double-buffered, reg prefetch, one barrier/tile;
// 64 VGPR + 64 AGPR -> 4 blocks/CU); sigma-permuted PV (lane's P fragments =
// its own QK^T outputs); raw v_exp_f32 softmax; VALU 4-partial row-sum kept
// as half-wave partial (one cross-lane combine at epilogue, not per iter);
// max3-tree local max; vote-gated rescale.
// ---------------------------------------------------------------------------
__global__ __launch_bounds__(256, 4) void attn_kernel(
    const half_t* __restrict__ Q, const half_t* __restrict__ K,
    const half_t* __restrict__ Vt, half_t* __restrict__ Op,
    float* __restrict__ Mp, float* __restrict__ Lp, int NS)
{
    __shared__ __align__(16) half_t Ks[2][64 * 64];   // swizzled [s][h]
    __shared__ __align__(16) half_t Vs[2][64 * 64];   // swizzled+permuted [d][slot]

    const int tid  = threadIdx.x;
    const int wave = tid >> 6;
    const int lane = tid & 63;
    const int qb   = blockIdx.x / NS;
    const int sp   = blockIdx.x - qb * NS;
    const int b    = qb >> 5;
    const int t0   = (qb & 31) << 7;       // 128 q-rows per block
    const int q0   = t0 + wave * 32;
    const int lq   = lane & 31;
    const int hi   = lane >> 5;
    const int NT   = T_ / (64 * NS);
    const int sbase = sp * (T_ / NS);

    // Q B-fragments (col=q, k=h): qf[kc][e] = Q[q0+lq][kc*16 + hi*8 + e]
    halfx8 qf[4];
    const half_t* qr = Q + ((size_t)b * T_ + q0 + lq) * H_ + hi * 8;
    #pragma unroll
    for (int kc = 0; kc < 4; ++kc) qf[kc] = *(const halfx8*)(qr + kc * 16);

    f32x16 oacc[2] = {};                    // O^T [2 d-tiles of 32][q]
    float mr = -INFINITY, lr = 0.f;         // lr = half-wave PARTIAL sum

    // staging: thread owns 2 x 16B chunks of K and of V per tile
    const int r0 = tid >> 3;
    const int c8 = (tid & 7) * 8;
    const int gA = (c8 & ~15) + ((c8 & 8) >> 1);   // V quad-permuted col A
    const half_t* kp = K  + (size_t)b * T_ * H_ + (size_t)(sbase + r0) * H_ + c8;
    const half_t* vp = Vt + (size_t)b * H_ * T_ + (size_t)r0 * T_ + sbase + c8;

    halfx8 rK0 = *(const halfx8*)kp;
    halfx8 rK1 = *(const halfx8*)(kp + 32 * H_);
    halfx8 rV0 = *(const halfx8*)vp;
    halfx8 rV1 = *(const halfx8*)(vp + 32 * T_);
    kp += 64 * H_; vp += 64;

    {
        *(halfx8*)&Ks[0][swz(r0, c8)]      = rK0;
        *(halfx8*)&Ks[0][swz(r0 + 32, c8)] = rK1;
        union { halfx8 h8; halfx4 h4[2]; } u0, u1;
        u0.h8 = rV0; u1.h8 = rV1;
        *(halfx4*)&Vs[0][swz4(r0, gA)]          = u0.h4[0];
        *(halfx4*)&Vs[0][swz4(r0, gA + 8)]      = u0.h4[1];
        *(halfx4*)&Vs[0][swz4(r0 + 32, gA)]     = u1.h4[0];
        *(halfx4*)&Vs[0][swz4(r0 + 32, gA + 8)] = u1.h4[1];
    }
    __syncthreads();

    for (int t = 0; t < NT; ++t) {
        const int cur = t & 1;
        const bool more = (t + 1 < NT);
        if (more) {
            rK0 = *(const halfx8*)kp;
            rK1 = *(const halfx8*)(kp + 32 * H_);
            rV0 = *(const halfx8*)vp;
            rV1 = *(const halfx8*)(vp + 32 * T_);
            kp += 64 * H_; vp += 64;
        }

        // ---- S^T = K . Q^T : 2 s-tiles of 32, K-dim 64 = 4 chunks ----
        f32x16 sacc[2] = {};
        __builtin_amdgcn_s_setprio(1);
        #pragma unroll
        for (int st = 0; st < 2; ++st)
            #pragma unroll
            for (int kc = 0; kc < 4; ++kc) {
                halfx8 kf = *(const halfx8*)&Ks[cur][swz(st * 32 + lq, kc * 16 + hi * 8)];
                sacc[st] = __builtin_amdgcn_mfma_f32_32x32x16_f16(kf, qf[kc], sacc[st], 0, 0, 0);
            }
        __builtin_amdgcn_s_setprio(0);

        // ---- local max via max3 tree (no cross-lane on common path) ----
        float pm;
        {
            float a0 = max3f(sacc[0][0],  sacc[0][1],  sacc[0][2]);
            float a1 = max3f(sacc[0][3],  sacc[0][4],  sacc[0][5]);
            float a2 = max3f(sacc[0][6],  sacc[0][7],  sacc[0][8]);
            float a3 = max3f(sacc[0][9],  sacc[0][10], sacc[0][11]);
            float a4 = max3f(sacc[0][12], sacc[0][13], sacc[0][14]);
            float b0 = max3f(sacc[1][0],  sacc[1][1],  sacc[1][2]);
            float b1 = max3f(sacc[1][3],  sacc[1][4],  sacc[1][5]);
            float b2 = max3f(sacc[1][6],  sacc[1][7],  sacc[1][8]);
            float b3 = max3f(sacc[1][9],  sacc[1][10], sacc[1][11]);
            float b4 = max3f(sacc[1][12], sacc[1][13], sacc[1][14]);
            float c0 = max3f(a0, a1, sacc[0][15]);
            float c1 = max3f(a2, a3, a4);
            float c2 = max3f(b0, b1, sacc[1][15]);
            float c3 = max3f(b2, b3, b4);
            pm = fmaxf(max3f(c0, c1, c2), c3);
        }
        if (__any(pm > mr + 8.f)) {        // defer-max rescale (rare)
            pm = fmaxf(pm, __shfl_xor(pm, 32));
            float mnew  = fmaxf(mr, pm);
            float scale = fast_exp2(mr - mnew);   // synced between partners
            mr = mnew; lr *= scale;
            #pragma unroll
            for (int dt = 0; dt < 2; ++dt)
                #pragma unroll
                for (int r = 0; r < 16; ++r) oacc[dt][r] *= scale;
        }
        // ---- exp + row-sum on VALU (4 partials for ILP; half-wave only) ----
        float p0 = 0.f, p1 = 0.f, p2 = 0.f, p3 = 0.f;
        #pragma unroll
        for (int st = 0; st < 2; ++st) {
            #pragma unroll
            for (int r = 0; r < 16; r += 4) {
                float e0 = fast_exp2(sacc[st][r + 0] - mr);
                float e1 = fast_exp2(sacc[st][r + 1] - mr);
                float e2 = fast_exp2(sacc[st][r + 2] - mr);
                float e3 = fast_exp2(sacc[st][r + 3] - mr);
                sacc[st][r + 0] = e0; sacc[st][r + 1] = e1;
                sacc[st][r + 2] = e2; sacc[st][r + 3] = e3;
                p0 += e0; p1 += e1; p2 += e2; p3 += e3;
            }
        }
        lr += (p0 + p1) + (p2 + p3);

        // ---- P^T B-fragments: lane's OWN regs (sigma-permuted k-order) ----
        halfx8 pfrag[4];
        #pragma unroll
        for (int sc = 0; sc < 4; ++sc) {
            const int st = sc >> 1, rb = (sc & 1) * 8;
            i32x4 w;
            w[0] = pk2i(sacc[st][rb + 0], sacc[st][rb + 1]);
            w[1] = pk2i(sacc[st][rb + 2], sacc[st][rb + 3]);
            w[2] = pk2i(sacc[st][rb + 4], sacc[st][rb + 5]);
            w[3] = pk2i(sacc[st][rb + 6], sacc[st][rb + 7]);
            pfrag[sc] = __builtin_bit_cast(halfx8, w);
        }

        // ---- O^T += V^T . P^T ----
        __builtin_amdgcn_s_setprio(1);
        #pragma unroll
        for (int sc = 0; sc < 4; ++sc) {
            halfx8 vf0 = *(const halfx8*)&Vs[cur][swz(lq,      sc * 16 + hi * 8)];
            halfx8 vf1 = *(const halfx8*)&Vs[cur][swz(32 + lq, sc * 16 + hi * 8)];
            oacc[0] = __builtin_amdgcn_mfma_f32_32x32x16_f16(vf0, pfrag[sc], oacc[0], 0, 0, 0);
            oacc[1] = __builtin_amdgcn_mfma_f32_32x32x16_f16(vf1, pfrag[sc], oacc[1], 0, 0, 0);
        }
        __builtin_amdgcn_s_setprio(0);

        if (more) {
            const int nxt = cur ^ 1;
            *(halfx8*)&Ks[nxt][swz(r0, c8)]      = rK0;
            *(halfx8*)&Ks[nxt][swz(r0 + 32, c8)] = rK1;
            union { halfx8 h8; halfx4 h4[2]; } u0, u1;
            u0.h8 = rV0; u1.h8 = rV1;
            *(halfx4*)&Vs[nxt][swz4(r0, gA)]          = u0.h4[0];
            *(halfx4*)&Vs[nxt][swz4(r0, gA + 8)]      = u0.h4[1];
            *(halfx4*)&Vs[nxt][swz4(r0 + 32, gA)]     = u1.h4[0];
            *(halfx4*)&Vs[nxt][swz4(r0 + 32, gA + 8)] = u1.h4[1];
            __syncthreads();
        }
    }

    // ---- epilogue: combine half-wave l partials, normalize, write ----
    const int BT = B_ * T_;
    const int grow = b * T_ + q0 + lq;
    const float lrt = lr + __shfl_xor(lr, 32);
    float inv = 1.f / lrt;
    half_t* od = Op + ((size_t)sp * BT + grow) * H_;
    #pragma unroll
    for (int dt = 0; dt < 2; ++dt)
        #pragma unroll
        for (int g = 0; g < 4; ++g) {
            union { halfx2 h2[2]; halfx4 h4; } u;
            u.h2[0] = pk2(oacc[dt][g * 4 + 0] * inv, oacc[dt][g * 4 + 1] * inv);
            u.h2[1] = pk2(oacc[dt][g * 4 + 2] * inv, oacc[dt][g * 4 + 3] * inv);
            *(halfx4*)(od + dt * 32 + g * 8 + hi * 4) = u.h4;
        }
    if (Mp != nullptr && hi == 0) {
        Mp[(size_t)sp * BT + grow] = mr;
        Lp[(size_t)sp * BT + grow] = lrt;
    }
}

// ---------------------------------------------------------------------------
// Kernel 3: fused merge + out-projection.
// Stages merged O (softmax split-merge over NS partials, weights
// w_i = l_i * 2^(m_i - m*)) directly into LDS, then
// out = x + b_out + w_out[128,64] @ O^T.
// ---------------------------------------------------------------------------
__global__ __launch_bounds__(256) void outproj_kernel(
    const half_t* __restrict__ Op, const float* __restrict__ Mp,
    const float* __restrict__ Lp, int NS,
    const float* __restrict__ w_out, const float* __restrict__ b_out,
    const float* __restrict__ x, float* __restrict__ out)
{
    __shared__ __align__(16) half_t Ot[64][72];   // [t][h] (merged)

    const int tid  = threadIdx.x;
    const int lane = tid & 63;
    const int wave = tid >> 6;
    const int b    = blockIdx.x >> 6;
    const int t0   = (blockIdx.x & 63) << 6;

    const int rowA  = lane & 15;
    const int kgrp  = lane >> 4;
    const int row_d = kgrp << 2;
    const int BT    = B_ * T_;

    #pragma unroll
    for (int it = 0; it < 2; ++it) {
        int q = it * 256 + tid;
        int t = q >> 3, hc = (q & 7) * 8;
        const size_t row = (size_t)b * T_ + t0 + t;
        if (Mp == nullptr) {
            *(halfx8*)&Ot[t][hc] = *(const halfx8*)(Op + row * H_ + hc);
        } else {
            float m = Mp[row];
            for (int s = 1; s < NS; ++s) m = fmaxf(m, Mp[(size_t)s * BT + row]);
            float W = 0.f;
            float acc[8] = {};
            for (int s = 0; s < NS; ++s) {
                float w = Lp[(size_t)s * BT + row] *
                          __builtin_amdgcn_exp2f(Mp[(size_t)s * BT + row] - m);
                W += w;
                halfx8 o = *(const halfx8*)(Op + ((size_t)s * BT + row) * H_ + hc);
                #pragma unroll
                for (int j = 0; j < 8; ++j) acc[j] += w * (float)o[j];
            }
            float inv = 1.f / W;
            halfx8 r;
            #pragma unroll
            for (int j = 0; j < 8; ++j) r[j] = (half_t)(acc[j] * inv);
            *(halfx8*)&Ot[t][hc] = r;
        }
    }

    const int c0 = wave * 32;
    halfx8 wf[2][2];
    #pragma unroll
    for (int ct = 0; ct < 2; ++ct) {
        const float* wrow = w_out + (size_t)(c0 + ct * 16 + rowA) * H_;
        #pragma unroll
        for (int hc = 0; hc < 2; ++hc) {
            const float* p = wrow + hc * 32 + kgrp * 8;
            f32x4 a = *(const f32x4*)p;
            f32x4 c2 = *(const f32x4*)(p + 4);
            halfx8 f;
            f[0]=(half_t)a[0]; f[1]=(half_t)a[1]; f[2]=(half_t)a[2]; f[3]=(half_t)a[3];
            f[4]=(half_t)c2[0];f[5]=(half_t)c2[1];f[6]=(half_t)c2[2];f[7]=(half_t)c2[3];
            wf[ct][hc] = f;
        }
    }

    __syncthreads();

    #pragma unroll
    for (int ct = 0; ct < 2; ++ct) {
        #pragma unroll
        for (int tt = 0; tt < 4; ++tt) {
            f32x4 acc = {};
            #pragma unroll
            for (int hc = 0; hc < 2; ++hc) {
                halfx8 of = *(const halfx8*)&Ot[tt * 16 + rowA][hc * 32 + kgrp * 8];
                acc = __builtin_amdgcn_mfma_f32_16x16x32_f16(wf[ct][hc], of, acc, 0, 0, 0);
            }
            const int c = c0 + ct * 16 + row_d;
            const size_t base = (size_t)b * C_ * T_ + t0 + tt * 16 + rowA;
            #pragma unroll
            for (int r = 0; r < 4; ++r) {
                size_t idx = base + (size_t)(c + r) * T_;
                out[idx] = x[idx] + b_out[c + r] + acc[r];
            }
        }
    }
}

// ---------------------------------------------------------------------------
extern "C" void kernel_launch(void* const* d_in, const int* in_sizes, int n_in,
                              void* d_out, int out_size, void* d_ws, size_t ws_size,
                              hipStream_t stream) {
    const float* x       = (const float*)d_in[0];
    const float* w_theta = (const float*)d_in[1];
    const float* b_theta = (const float*)d_in[2];
    const float* w_phi   = (const float*)d_in[3];
    const float* b_phi   = (const float*)d_in[4];
    const float* w_g     = (const float*)d_in[5];
    const float* b_g     = (const float*)d_in[6];
    const float* w_out   = (const float*)d_in[7];
    const float* b_out   = (const float*)d_in[8];
    float* out = (float*)d_out;

    const size_t mat = (size_t)B_ * T_ * H_;   // 2 M elements
    const size_t BT  = (size_t)B_ * T_;        // 32768 rows
    half_t* Qw = (half_t*)d_ws;
    half_t* Kw = Qw + mat;
    half_t* Vw = Kw + mat;
    half_t* Ow = Vw + mat;                     // base: 16 MB
    const size_t base_b = 4 * mat * sizeof(half_t);

    auto need = [&](size_t ns) { return base_b + ns * mat * 2 + ns * BT * 8; };
    const int NS = (ws_size >= need(4)) ? 4 : ((ws_size >= need(2)) ? 2 : 1);

    half_t* Opart = Ow;
    float*  Mp = nullptr;
    float*  Lp = nullptr;
    if (NS > 1) {
        Opart = (half_t*)((char*)d_ws + base_b);
        Mp = (float*)((char*)d_ws + base_b + (size_t)NS * mat * 2);
        Lp = Mp + (size_t)NS * BT;
    }

    proj_kernel<<<dim3(B_ * (T_ / 64)), dim3(256), 0, stream>>>(
        x, w_theta, b_theta, w_phi, b_phi, w_g, b_g, Qw, Kw, Vw);
    attn_kernel<<<dim3(B_ * (T_ / 128) * NS), dim3(256), 0, stream>>>(
        Qw, Kw, Vw, Opart, Mp, Lp, NS);
    outproj_kernel<<<dim3(B_ * (T_ / 64)), dim3(256), 0, stream>>>(
        Opart, Mp, Lp, NS, w_out, b_out, x, out);
}

// Round 15
// 76.381 us; speedup vs baseline: 1.1026x; 1.1026x over previous
//
#include <hip/hip_runtime.h>
#include <hip/hip_bf16.h>

typedef _Float16 half_t;
typedef half_t halfx8 __attribute__((ext_vector_type(8)));
typedef half_t halfx4 __attribute__((ext_vector_type(4)));
typedef half_t halfx2 __attribute__((ext_vector_type(2)));
typedef __fp16 fp16x2 __attribute__((ext_vector_type(2)));
typedef float f32x4 __attribute__((ext_vector_type(4)));
typedef float f32x16 __attribute__((ext_vector_type(16)));
typedef int i32x4 __attribute__((ext_vector_type(4)));

#define B_ 8
#define C_ 128
#define T_ 4096
#define H_ 64
#define L2E 1.44269504088896340736f

static __device__ __forceinline__ halfx2 pk2(float a, float b) {
    fp16x2 r = __builtin_amdgcn_cvt_pkrtz(a, b);
    return __builtin_bit_cast(halfx2, r);
}
static __device__ __forceinline__ int pk2i(float a, float b) {
    return __builtin_bit_cast(int, __builtin_amdgcn_cvt_pkrtz(a, b));
}
// bare v_exp_f32 (exp2): avoids the ~6-instr __ocml_exp2_f32 denormal wrapper.
static __device__ __forceinline__ float fast_exp2(float x) {
    return __builtin_amdgcn_exp2f(x);
}
static __device__ __forceinline__ float max3f(float a, float b, float c) {
    return fmaxf(fmaxf(a, b), c);   // clang fuses to v_max3_f32
}
// XOR-swizzle for 64-col (128B-row) LDS tiles; col multiple of 8
static __device__ __forceinline__ int swz(int row, int col) {
    return (row << 6) + (col ^ ((row & 7) << 3));
}
// same swizzle, col multiple of 4 (quad-granular writes)
static __device__ __forceinline__ int swz4(int row, int col) {
    return (row << 6) + ((col & ~7) ^ ((row & 7) << 3)) + (col & 7);
}

// ---------------------------------------------------------------------------
// Kernel 1: projections. theta/phi/g = W[64,128] @ x[b][128, t-tile(64)] + bias
// Q (theta, pre-scaled by log2e) [B,T,H], K (phi) [B,T,H], Vt (g) [B,H,T], f16
// ---------------------------------------------------------------------------
__global__ __launch_bounds__(256) void proj_kernel(
    const float* __restrict__ x,
    const float* __restrict__ w_theta, const float* __restrict__ b_theta,
    const float* __restrict__ w_phi,   const float* __restrict__ b_phi,
    const float* __restrict__ w_g,     const float* __restrict__ b_g,
    half_t* __restrict__ Q, half_t* __restrict__ Ko, half_t* __restrict__ Vt)
{
    __shared__ __align__(16) half_t xt[64][136];   // [t][c]
    __shared__ __align__(16) half_t ts[64][72];    // transpose buf [t][h]

    const int tid  = threadIdx.x;
    const int lane = tid & 63;
    const int wave = tid >> 6;
    const int b    = blockIdx.x >> 6;
    const int t0   = (blockIdx.x & 63) << 6;

    const int rowA  = lane & 15;
    const int kgrp  = lane >> 4;
    const int row_d = kgrp << 2;

    const float* xb = x + (size_t)b * C_ * T_ + t0;
    #pragma unroll
    for (int it = 0; it < 8; ++it) {
        int li = it * 256 + tid;
        int c  = li >> 4;
        int tc = li & 15;
        f32x4 v = *(const f32x4*)(xb + (size_t)c * T_ + tc * 4);
        #pragma unroll
        for (int j = 0; j < 4; ++j) xt[tc * 4 + j][c] = (half_t)v[j];
    }

    const int h0 = wave << 4;
    const float* Ws[3] = {w_theta, w_phi, w_g};
    const float* Bs[3] = {b_theta, b_phi, b_g};
    halfx8 wa[3][4];
    #pragma unroll
    for (int m = 0; m < 3; ++m) {
        const float* wrow = Ws[m] + (size_t)(h0 + rowA) * C_;
        #pragma unroll
        for (int cc = 0; cc < 4; ++cc) {
            const float* p = wrow + cc * 32 + kgrp * 8;
            f32x4 a = *(const f32x4*)p;
            f32x4 c2 = *(const f32x4*)(p + 4);
            halfx8 f;
            f[0]=(half_t)a[0]; f[1]=(half_t)a[1]; f[2]=(half_t)a[2]; f[3]=(half_t)a[3];
            f[4]=(half_t)c2[0];f[5]=(half_t)c2[1];f[6]=(half_t)c2[2];f[7]=(half_t)c2[3];
            wa[m][cc] = f;
        }
    }

    __syncthreads();

    #pragma unroll
    for (int m = 0; m < 3; ++m) {
        f32x4 acc[4] = {};
        #pragma unroll
        for (int tt = 0; tt < 4; ++tt) {
            #pragma unroll
            for (int cc = 0; cc < 4; ++cc) {
                halfx8 bfrag = *(const halfx8*)&xt[tt * 16 + rowA][cc * 32 + kgrp * 8];
                acc[tt] = __builtin_amdgcn_mfma_f32_16x16x32_f16(wa[m][cc], bfrag, acc[tt], 0, 0, 0);
            }
        }
        float bias[4];
        #pragma unroll
        for (int r = 0; r < 4; ++r) bias[r] = Bs[m][h0 + row_d + r];

        if (m < 2) {
            const float sc = (m == 0) ? L2E : 1.0f;   // fold log2e into theta
            #pragma unroll
            for (int tt = 0; tt < 4; ++tt)
                #pragma unroll
                for (int r = 0; r < 4; ++r)
                    ts[tt * 16 + rowA][h0 + row_d + r] = (half_t)((acc[tt][r] + bias[r]) * sc);
            __syncthreads();
            half_t* dst = (m == 0 ? Q : Ko) + ((size_t)b * T_ + t0) * H_;
            #pragma unroll
            for (int it = 0; it < 2; ++it) {
                int q = it * 256 + tid;
                int t = q >> 3, hc = q & 7;
                *(halfx8*)(dst + (size_t)t * H_ + hc * 8) = *(const halfx8*)&ts[t][hc * 8];
            }
            __syncthreads();
        } else {
            half_t* dst = Vt + (size_t)b * H_ * T_ + t0;
            #pragma unroll
            for (int tt = 0; tt < 4; ++tt)
                #pragma unroll
                for (int r = 0; r < 4; ++r)
                    dst[(size_t)(h0 + row_d + r) * T_ + tt * 16 + rowA] = (half_t)(acc[tt][r] + bias[r]);
        }
    }
}

// ---------------------------------------------------------------------------
// Kernel 2: flash attention, 32x32 MFMA swapped-operand + KV-split (NS=4).
// EXACT R13 loop (proven 55.6 us): K+V in XOR-swizzled LDS (double-buffered,
// reg prefetch, one barrier/tile; 64 VGPR + 64 AGPR -> 4 blocks/CU);
// sigma-permuted PV; raw v_exp_f32 softmax; VALU 4-partial row-sum with
// per-iter cross-lane combine (removing it perturbed scheduling, R14 -18%);
// max3-tree local max; vote-gated rescale.
// ---------------------------------------------------------------------------
__global__ __launch_bounds__(256, 4) void attn_kernel(
    const half_t* __restrict__ Q, const half_t* __restrict__ K,
    const half_t* __restrict__ Vt, half_t* __restrict__ Op,
    float* __restrict__ Mp, float* __restrict__ Lp, int NS)
{
    __shared__ __align__(16) half_t Ks[2][64 * 64];   // swizzled [s][h]
    __shared__ __align__(16) half_t Vs[2][64 * 64];   // swizzled+permuted [d][slot]

    const int tid  = threadIdx.x;
    const int wave = tid >> 6;
    const int lane = tid & 63;
    const int qb   = blockIdx.x / NS;
    const int sp   = blockIdx.x - qb * NS;
    const int b    = qb >> 5;
    const int t0   = (qb & 31) << 7;       // 128 q-rows per block
    const int q0   = t0 + wave * 32;
    const int lq   = lane & 31;
    const int hi   = lane >> 5;
    const int NT   = T_ / (64 * NS);
    const int sbase = sp * (T_ / NS);

    // Q B-fragments (col=q, k=h): qf[kc][e] = Q[q0+lq][kc*16 + hi*8 + e]
    halfx8 qf[4];
    const half_t* qr = Q + ((size_t)b * T_ + q0 + lq) * H_ + hi * 8;
    #pragma unroll
    for (int kc = 0; kc < 4; ++kc) qf[kc] = *(const halfx8*)(qr + kc * 16);

    f32x16 oacc[2] = {};                    // O^T [2 d-tiles of 32][q]
    float mr = -INFINITY, lr = 0.f;

    // staging: thread owns 2 x 16B chunks of K and of V per tile
    const int r0 = tid >> 3;
    const int c8 = (tid & 7) * 8;
    const int gA = (c8 & ~15) + ((c8 & 8) >> 1);   // V quad-permuted col A
    const half_t* kp = K  + (size_t)b * T_ * H_ + (size_t)(sbase + r0) * H_ + c8;
    const half_t* vp = Vt + (size_t)b * H_ * T_ + (size_t)r0 * T_ + sbase + c8;

    halfx8 rK0 = *(const halfx8*)kp;
    halfx8 rK1 = *(const halfx8*)(kp + 32 * H_);
    halfx8 rV0 = *(const halfx8*)vp;
    halfx8 rV1 = *(const halfx8*)(vp + 32 * T_);
    kp += 64 * H_; vp += 64;

    {
        *(halfx8*)&Ks[0][swz(r0, c8)]      = rK0;
        *(halfx8*)&Ks[0][swz(r0 + 32, c8)] = rK1;
        union { halfx8 h8; halfx4 h4[2]; } u0, u1;
        u0.h8 = rV0; u1.h8 = rV1;
        *(halfx4*)&Vs[0][swz4(r0, gA)]          = u0.h4[0];
        *(halfx4*)&Vs[0][swz4(r0, gA + 8)]      = u0.h4[1];
        *(halfx4*)&Vs[0][swz4(r0 + 32, gA)]     = u1.h4[0];
        *(halfx4*)&Vs[0][swz4(r0 + 32, gA + 8)] = u1.h4[1];
    }
    __syncthreads();

    for (int t = 0; t < NT; ++t) {
        const int cur = t & 1;
        const bool more = (t + 1 < NT);
        if (more) {
            rK0 = *(const halfx8*)kp;
            rK1 = *(const halfx8*)(kp + 32 * H_);
            rV0 = *(const halfx8*)vp;
            rV1 = *(const halfx8*)(vp + 32 * T_);
            kp += 64 * H_; vp += 64;
        }

        // ---- S^T = K . Q^T : 2 s-tiles of 32, K-dim 64 = 4 chunks ----
        f32x16 sacc[2] = {};
        __builtin_amdgcn_s_setprio(1);
        #pragma unroll
        for (int st = 0; st < 2; ++st)
            #pragma unroll
            for (int kc = 0; kc < 4; ++kc) {
                halfx8 kf = *(const halfx8*)&Ks[cur][swz(st * 32 + lq, kc * 16 + hi * 8)];
                sacc[st] = __builtin_amdgcn_mfma_f32_32x32x16_f16(kf, qf[kc], sacc[st], 0, 0, 0);
            }
        __builtin_amdgcn_s_setprio(0);

        // ---- local max via max3 tree (no cross-lane on common path) ----
        float pm;
        {
            float a0 = max3f(sacc[0][0],  sacc[0][1],  sacc[0][2]);
            float a1 = max3f(sacc[0][3],  sacc[0][4],  sacc[0][5]);
            float a2 = max3f(sacc[0][6],  sacc[0][7],  sacc[0][8]);
            float a3 = max3f(sacc[0][9],  sacc[0][10], sacc[0][11]);
            float a4 = max3f(sacc[0][12], sacc[0][13], sacc[0][14]);
            float b0 = max3f(sacc[1][0],  sacc[1][1],  sacc[1][2]);
            float b1 = max3f(sacc[1][3],  sacc[1][4],  sacc[1][5]);
            float b2 = max3f(sacc[1][6],  sacc[1][7],  sacc[1][8]);
            float b3 = max3f(sacc[1][9],  sacc[1][10], sacc[1][11]);
            float b4 = max3f(sacc[1][12], sacc[1][13], sacc[1][14]);
            float c0 = max3f(a0, a1, sacc[0][15]);
            float c1 = max3f(a2, a3, a4);
            float c2 = max3f(b0, b1, sacc[1][15]);
            float c3 = max3f(b2, b3, b4);
            pm = fmaxf(max3f(c0, c1, c2), c3);
        }
        if (__any(pm > mr + 8.f)) {        // defer-max rescale (rare)
            pm = fmaxf(pm, __shfl_xor(pm, 32));
            float mnew  = fmaxf(mr, pm);
            float scale = fast_exp2(mr - mnew);
            mr = mnew; lr *= scale;
            #pragma unroll
            for (int dt = 0; dt < 2; ++dt)
                #pragma unroll
                for (int r = 0; r < 16; ++r) oacc[dt][r] *= scale;
        }
        // ---- exp + row-sum on VALU (4 partials for ILP) ----
        float p0 = 0.f, p1 = 0.f, p2 = 0.f, p3 = 0.f;
        #pragma unroll
        for (int st = 0; st < 2; ++st) {
            #pragma unroll
            for (int r = 0; r < 16; r += 4) {
                float e0 = fast_exp2(sacc[st][r + 0] - mr);
                float e1 = fast_exp2(sacc[st][r + 1] - mr);
                float e2 = fast_exp2(sacc[st][r + 2] - mr);
                float e3 = fast_exp2(sacc[st][r + 3] - mr);
                sacc[st][r + 0] = e0; sacc[st][r + 1] = e1;
                sacc[st][r + 2] = e2; sacc[st][r + 3] = e3;
                p0 += e0; p1 += e1; p2 += e2; p3 += e3;
            }
        }
        float ps = (p0 + p1) + (p2 + p3);
        lr += ps + __shfl_xor(ps, 32);

        // ---- P^T B-fragments: lane's OWN regs (sigma-permuted k-order) ----
        halfx8 pfrag[4];
        #pragma unroll
        for (int sc = 0; sc < 4; ++sc) {
            const int st = sc >> 1, rb = (sc & 1) * 8;
            i32x4 w;
            w[0] = pk2i(sacc[st][rb + 0], sacc[st][rb + 1]);
            w[1] = pk2i(sacc[st][rb + 2], sacc[st][rb + 3]);
            w[2] = pk2i(sacc[st][rb + 4], sacc[st][rb + 5]);
            w[3] = pk2i(sacc[st][rb + 6], sacc[st][rb + 7]);
            pfrag[sc] = __builtin_bit_cast(halfx8, w);
        }

        // ---- O^T += V^T . P^T ----
        __builtin_amdgcn_s_setprio(1);
        #pragma unroll
        for (int sc = 0; sc < 4; ++sc) {
            halfx8 vf0 = *(const halfx8*)&Vs[cur][swz(lq,      sc * 16 + hi * 8)];
            halfx8 vf1 = *(const halfx8*)&Vs[cur][swz(32 + lq, sc * 16 + hi * 8)];
            oacc[0] = __builtin_amdgcn_mfma_f32_32x32x16_f16(vf0, pfrag[sc], oacc[0], 0, 0, 0);
            oacc[1] = __builtin_amdgcn_mfma_f32_32x32x16_f16(vf1, pfrag[sc], oacc[1], 0, 0, 0);
        }
        __builtin_amdgcn_s_setprio(0);

        if (more) {
            const int nxt = cur ^ 1;
            *(halfx8*)&Ks[nxt][swz(r0, c8)]      = rK0;
            *(halfx8*)&Ks[nxt][swz(r0 + 32, c8)] = rK1;
            union { halfx8 h8; halfx4 h4[2]; } u0, u1;
            u0.h8 = rV0; u1.h8 = rV1;
            *(halfx4*)&Vs[nxt][swz4(r0, gA)]          = u0.h4[0];
            *(halfx4*)&Vs[nxt][swz4(r0, gA + 8)]      = u0.h4[1];
            *(halfx4*)&Vs[nxt][swz4(r0 + 32, gA)]     = u1.h4[0];
            *(halfx4*)&Vs[nxt][swz4(r0 + 32, gA + 8)] = u1.h4[1];
            __syncthreads();
        }
    }

    // ---- epilogue: normalized partial O (f16) + m,l ----
    const int BT = B_ * T_;
    const int grow = b * T_ + q0 + lq;
    float inv = 1.f / lr;
    half_t* od = Op + ((size_t)sp * BT + grow) * H_;
    #pragma unroll
    for (int dt = 0; dt < 2; ++dt)
        #pragma unroll
        for (int g = 0; g < 4; ++g) {
            union { halfx2 h2[2]; halfx4 h4; } u;
            u.h2[0] = pk2(oacc[dt][g * 4 + 0] * inv, oacc[dt][g * 4 + 1] * inv);
            u.h2[1] = pk2(oacc[dt][g * 4 + 2] * inv, oacc[dt][g * 4 + 3] * inv);
            *(halfx4*)(od + dt * 32 + g * 8 + hi * 4) = u.h4;
        }
    if (Mp != nullptr && hi == 0) {
        Mp[(size_t)sp * BT + grow] = mr;
        Lp[(size_t)sp * BT + grow] = lr;
    }
}

// ---------------------------------------------------------------------------
// Kernel 3: fused merge + out-projection.
// Stages merged O (softmax split-merge over NS partials, weights
// w_i = l_i * 2^(m_i - m*)) directly into LDS, then
// out = x + b_out + w_out[128,64] @ O^T.
// ---------------------------------------------------------------------------
__global__ __launch_bounds__(256) void outproj_kernel(
    const half_t* __restrict__ Op, const float* __restrict__ Mp,
    const float* __restrict__ Lp, int NS,
    const float* __restrict__ w_out, const float* __restrict__ b_out,
    const float* __restrict__ x, float* __restrict__ out)
{
    __shared__ __align__(16) half_t Ot[64][72];   // [t][h] (merged)

    const int tid  = threadIdx.x;
    const int lane = tid & 63;
    const int wave = tid >> 6;
    const int b    = blockIdx.x >> 6;
    const int t0   = (blockIdx.x & 63) << 6;

    const int rowA  = lane & 15;
    const int kgrp  = lane >> 4;
    const int row_d = kgrp << 2;
    const int BT    = B_ * T_;

    #pragma unroll
    for (int it = 0; it < 2; ++it) {
        int q = it * 256 + tid;
        int t = q >> 3, hc = (q & 7) * 8;
        const size_t row = (size_t)b * T_ + t0 + t;
        if (Mp == nullptr) {
            *(halfx8*)&Ot[t][hc] = *(const halfx8*)(Op + row * H_ + hc);
        } else {
            float m = Mp[row];
            for (int s = 1; s < NS; ++s) m = fmaxf(m, Mp[(size_t)s * BT + row]);
            float W = 0.f;
            float acc[8] = {};
            for (int s = 0; s < NS; ++s) {
                float w = Lp[(size_t)s * BT + row] *
                          __builtin_amdgcn_exp2f(Mp[(size_t)s * BT + row] - m);
                W += w;
                halfx8 o = *(const halfx8*)(Op + ((size_t)s * BT + row) * H_ + hc);
                #pragma unroll
                for (int j = 0; j < 8; ++j) acc[j] += w * (float)o[j];
            }
            float inv = 1.f / W;
            halfx8 r;
            #pragma unroll
            for (int j = 0; j < 8; ++j) r[j] = (half_t)(acc[j] * inv);
            *(halfx8*)&Ot[t][hc] = r;
        }
    }

    const int c0 = wave * 32;
    halfx8 wf[2][2];
    #pragma unroll
    for (int ct = 0; ct < 2; ++ct) {
        const float* wrow = w_out + (size_t)(c0 + ct * 16 + rowA) * H_;
        #pragma unroll
        for (int hc = 0; hc < 2; ++hc) {
            const float* p = wrow + hc * 32 + kgrp * 8;
            f32x4 a = *(const f32x4*)p;
            f32x4 c2 = *(const f32x4*)(p + 4);
            halfx8 f;
            f[0]=(half_t)a[0]; f[1]=(half_t)a[1]; f[2]=(half_t)a[2]; f[3]=(half_t)a[3];
            f[4]=(half_t)c2[0];f[5]=(half_t)c2[1];f[6]=(half_t)c2[2];f[7]=(half_t)c2[3];
            wf[ct][hc] = f;
        }
    }

    __syncthreads();

    #pragma unroll
    for (int ct = 0; ct < 2; ++ct) {
        #pragma unroll
        for (int tt = 0; tt < 4; ++tt) {
            f32x4 acc = {};
            #pragma unroll
            for (int hc = 0; hc < 2; ++hc) {
                halfx8 of = *(const halfx8*)&Ot[tt * 16 + rowA][hc * 32 + kgrp * 8];
                acc = __builtin_amdgcn_mfma_f32_16x16x32_f16(wf[ct][hc], of, acc, 0, 0, 0);
            }
            const int c = c0 + ct * 16 + row_d;
            const size_t base = (size_t)b * C_ * T_ + t0 + tt * 16 + rowA;
            #pragma unroll
            for (int r = 0; r < 4; ++r) {
                size_t idx = base + (size_t)(c + r) * T_;
                out[idx] = x[idx] + b_out[c + r] + acc[r];
            }
        }
    }
}

// ---------------------------------------------------------------------------
extern "C" void kernel_launch(void* const* d_in, const int* in_sizes, int n_in,
                              void* d_out, int out_size, void* d_ws, size_t ws_size,
                              hipStream_t stream) {
    const float* x       = (const float*)d_in[0];
    const float* w_theta = (const float*)d_in[1];
    const float* b_theta = (const float*)d_in[2];
    const float* w_phi   = (const float*)d_in[3];
    const float* b_phi   = (const float*)d_in[4];
    const float* w_g     = (const float*)d_in[5];
    const float* b_g     = (const float*)d_in[6];
    const float* w_out   = (const float*)d_in[7];
    const float* b_out   = (const float*)d_in[8];
    float* out = (float*)d_out;

    const size_t mat = (size_t)B_ * T_ * H_;   // 2 M elements
    const size_t BT  = (size_t)B_ * T_;        // 32768 rows
    half_t* Qw = (half_t*)d_ws;
    half_t* Kw = Qw + mat;
    half_t* Vw = Kw + mat;
    half_t* Ow = Vw + mat;                     // base: 16 MB
    const size_t base_b = 4 * mat * sizeof(half_t);

    auto need = [&](size_t ns) { return base_b + ns * mat * 2 + ns * BT * 8; };
    const int NS = (ws_size >= need(4)) ? 4 : ((ws_size >= need(2)) ? 2 : 1);

    half_t* Opart = Ow;
    float*  Mp = nullptr;
    float*  Lp = nullptr;
    if (NS > 1) {
        Opart = (half_t*)((char*)d_ws + base_b);
        Mp = (float*)((char*)d_ws + base_b + (size_t)NS * mat * 2);
        Lp = Mp + (size_t)NS * BT;
    }

    proj_kernel<<<dim3(B_ * (T_ / 64)), dim3(256), 0, stream>>>(
        x, w_theta, b_theta, w_phi, b_phi, w_g, b_g, Qw, Kw, Vw);
    attn_kernel<<<dim3(B_ * (T_ / 128) * NS), dim3(256), 0, stream>>>(
        Qw, Kw, Vw, Opart, Mp, Lp, NS);
    outproj_kernel<<<dim3(B_ * (T_ / 64)), dim3(256), 0, stream>>>(
        Opart, Mp, Lp, NS, w_out, b_out, x, out);
}

// Round 16
// 75.862 us; speedup vs baseline: 1.1101x; 1.0068x over previous
//
#include <hip/hip_runtime.h>
#include <hip/hip_bf16.h>

typedef _Float16 half_t;
typedef half_t halfx8 __attribute__((ext_vector_type(8)));
typedef half_t halfx4 __attribute__((ext_vector_type(4)));
typedef half_t halfx2 __attribute__((ext_vector_type(2)));
typedef __fp16 fp16x2 __attribute__((ext_vector_type(2)));
typedef float f32x4 __attribute__((ext_vector_type(4)));
typedef float f32x16 __attribute__((ext_vector_type(16)));
typedef int i32x4 __attribute__((ext_vector_type(4)));

#define B_ 8
#define C_ 128
#define T_ 4096
#define H_ 64
#define L2E 1.44269504088896340736f

static __device__ __forceinline__ halfx2 pk2(float a, float b) {
    fp16x2 r = __builtin_amdgcn_cvt_pkrtz(a, b);
    return __builtin_bit_cast(halfx2, r);
}
static __device__ __forceinline__ int pk2i(float a, float b) {
    return __builtin_bit_cast(int, __builtin_amdgcn_cvt_pkrtz(a, b));
}
// bare v_exp_f32 (exp2): avoids the ~6-instr __ocml_exp2_f32 denormal wrapper.
static __device__ __forceinline__ float fast_exp2(float x) {
    return __builtin_amdgcn_exp2f(x);
}
static __device__ __forceinline__ float max3f(float a, float b, float c) {
    return fmaxf(fmaxf(a, b), c);   // clang fuses to v_max3_f32
}
// XOR-swizzle for 64-col (128B-row) LDS tiles; col multiple of 8
static __device__ __forceinline__ int swz(int row, int col) {
    return (row << 6) + (col ^ ((row & 7) << 3));
}
// same swizzle, col multiple of 4 (quad-granular writes)
static __device__ __forceinline__ int swz4(int row, int col) {
    return (row << 6) + ((col & ~7) ^ ((row & 7) << 3)) + (col & 7);
}

// ---------------------------------------------------------------------------
// Kernel 1: projections. theta/phi/g = W[64,128] @ x[b][128, t-tile(64)] + bias
// Q (theta, pre-scaled by log2e) [B,T,H], K (phi) [B,T,H], Vt (g) [B,H,T], f16
// ---------------------------------------------------------------------------
__global__ __launch_bounds__(256) void proj_kernel(
    const float* __restrict__ x,
    const float* __restrict__ w_theta, const float* __restrict__ b_theta,
    const float* __restrict__ w_phi,   const float* __restrict__ b_phi,
    const float* __restrict__ w_g,     const float* __restrict__ b_g,
    half_t* __restrict__ Q, half_t* __restrict__ Ko, half_t* __restrict__ Vt)
{
    __shared__ __align__(16) half_t xt[64][136];   // [t][c]
    __shared__ __align__(16) half_t ts[64][72];    // transpose buf [t][h]

    const int tid  = threadIdx.x;
    const int lane = tid & 63;
    const int wave = tid >> 6;
    const int b    = blockIdx.x >> 6;
    const int t0   = (blockIdx.x & 63) << 6;

    const int rowA  = lane & 15;
    const int kgrp  = lane >> 4;
    const int row_d = kgrp << 2;

    const float* xb = x + (size_t)b * C_ * T_ + t0;
    #pragma unroll
    for (int it = 0; it < 8; ++it) {
        int li = it * 256 + tid;
        int c  = li >> 4;
        int tc = li & 15;
        f32x4 v = *(const f32x4*)(xb + (size_t)c * T_ + tc * 4);
        #pragma unroll
        for (int j = 0; j < 4; ++j) xt[tc * 4 + j][c] = (half_t)v[j];
    }

    const int h0 = wave << 4;
    const float* Ws[3] = {w_theta, w_phi, w_g};
    const float* Bs[3] = {b_theta, b_phi, b_g};
    halfx8 wa[3][4];
    #pragma unroll
    for (int m = 0; m < 3; ++m) {
        const float* wrow = Ws[m] + (size_t)(h0 + rowA) * C_;
        #pragma unroll
        for (int cc = 0; cc < 4; ++cc) {
            const float* p = wrow + cc * 32 + kgrp * 8;
            f32x4 a = *(const f32x4*)p;
            f32x4 c2 = *(const f32x4*)(p + 4);
            halfx8 f;
            f[0]=(half_t)a[0]; f[1]=(half_t)a[1]; f[2]=(half_t)a[2]; f[3]=(half_t)a[3];
            f[4]=(half_t)c2[0];f[5]=(half_t)c2[1];f[6]=(half_t)c2[2];f[7]=(half_t)c2[3];
            wa[m][cc] = f;
        }
    }

    __syncthreads();

    #pragma unroll
    for (int m = 0; m < 3; ++m) {
        f32x4 acc[4] = {};
        #pragma unroll
        for (int tt = 0; tt < 4; ++tt) {
            #pragma unroll
            for (int cc = 0; cc < 4; ++cc) {
                halfx8 bfrag = *(const halfx8*)&xt[tt * 16 + rowA][cc * 32 + kgrp * 8];
                acc[tt] = __builtin_amdgcn_mfma_f32_16x16x32_f16(wa[m][cc], bfrag, acc[tt], 0, 0, 0);
            }
        }
        float bias[4];
        #pragma unroll
        for (int r = 0; r < 4; ++r) bias[r] = Bs[m][h0 + row_d + r];

        if (m < 2) {
            const float sc = (m == 0) ? L2E : 1.0f;   // fold log2e into theta
            #pragma unroll
            for (int tt = 0; tt < 4; ++tt)
                #pragma unroll
                for (int r = 0; r < 4; ++r)
                    ts[tt * 16 + rowA][h0 + row_d + r] = (half_t)((acc[tt][r] + bias[r]) * sc);
            __syncthreads();
            half_t* dst = (m == 0 ? Q : Ko) + ((size_t)b * T_ + t0) * H_;
            #pragma unroll
            for (int it = 0; it < 2; ++it) {
                int q = it * 256 + tid;
                int t = q >> 3, hc = q & 7;
                *(halfx8*)(dst + (size_t)t * H_ + hc * 8) = *(const halfx8*)&ts[t][hc * 8];
            }
            __syncthreads();
        } else {
            half_t* dst = Vt + (size_t)b * H_ * T_ + t0;
            #pragma unroll
            for (int tt = 0; tt < 4; ++tt)
                #pragma unroll
                for (int r = 0; r < 4; ++r)
                    dst[(size_t)(h0 + row_d + r) * T_ + tt * 16 + rowA] = (half_t)(acc[tt][r] + bias[r]);
        }
    }
}

// ---------------------------------------------------------------------------
// Kernel 2: flash attention, 32x32 MFMA swapped-operand + KV-split (NS=4).
// R15 loop body bit-identical (proven 55.6 us). Added: bijective XCD-affinity
// blockIdx swizzle (T1) so each XCD's private L2 holds a small set of KV
// slices: XCD x processes 4 contiguous (b,sp) groups (KV 1MB + Q 2MB < 4MB).
// Pure pre-loop scalar index math; loop scheduling untouched.
// ---------------------------------------------------------------------------
__global__ __launch_bounds__(256, 4) void attn_kernel(
    const half_t* __restrict__ Q, const half_t* __restrict__ K,
    const half_t* __restrict__ Vt, half_t* __restrict__ Op,
    float* __restrict__ Mp, float* __restrict__ Lp, int NS)
{
    __shared__ __align__(16) half_t Ks[2][64 * 64];   // swizzled [s][h]
    __shared__ __align__(16) half_t Vs[2][64 * 64];   // swizzled+permuted [d][slot]

    const int tid  = threadIdx.x;
    const int wave = tid >> 6;
    const int lane = tid & 63;

    // XCD-affinity swizzle: nwg = 256*NS (multiple of 8). XCD gets wg = x mod 8
    // round-robin; remap so its origs are contiguous -> 4 (b,sp) groups/XCD.
    const int nwg  = gridDim.x;
    const int perx = nwg >> 3;
    const int orig = (blockIdx.x & 7) * perx + (blockIdx.x >> 3);
    // decode orig = ((b*NS)+sp)*32 + qbi  (groups same-(b,sp) contiguously)
    const int grp  = orig >> 5;
    const int qbi  = orig & 31;
    const int sp   = grp % NS;
    const int b    = grp / NS;
    const int t0   = qbi << 7;             // 128 q-rows per block
    const int q0   = t0 + wave * 32;
    const int lq   = lane & 31;
    const int hi   = lane >> 5;
    const int NT   = T_ / (64 * NS);
    const int sbase = sp * (T_ / NS);

    // Q B-fragments (col=q, k=h): qf[kc][e] = Q[q0+lq][kc*16 + hi*8 + e]
    halfx8 qf[4];
    const half_t* qr = Q + ((size_t)b * T_ + q0 + lq) * H_ + hi * 8;
    #pragma unroll
    for (int kc = 0; kc < 4; ++kc) qf[kc] = *(const halfx8*)(qr + kc * 16);

    f32x16 oacc[2] = {};                    // O^T [2 d-tiles of 32][q]
    float mr = -INFINITY, lr = 0.f;

    // staging: thread owns 2 x 16B chunks of K and of V per tile
    const int r0 = tid >> 3;
    const int c8 = (tid & 7) * 8;
    const int gA = (c8 & ~15) + ((c8 & 8) >> 1);   // V quad-permuted col A
    const half_t* kp = K  + (size_t)b * T_ * H_ + (size_t)(sbase + r0) * H_ + c8;
    const half_t* vp = Vt + (size_t)b * H_ * T_ + (size_t)r0 * T_ + sbase + c8;

    halfx8 rK0 = *(const halfx8*)kp;
    halfx8 rK1 = *(const halfx8*)(kp + 32 * H_);
    halfx8 rV0 = *(const halfx8*)vp;
    halfx8 rV1 = *(const halfx8*)(vp + 32 * T_);
    kp += 64 * H_; vp += 64;

    {
        *(halfx8*)&Ks[0][swz(r0, c8)]      = rK0;
        *(halfx8*)&Ks[0][swz(r0 + 32, c8)] = rK1;
        union { halfx8 h8; halfx4 h4[2]; } u0, u1;
        u0.h8 = rV0; u1.h8 = rV1;
        *(halfx4*)&Vs[0][swz4(r0, gA)]          = u0.h4[0];
        *(halfx4*)&Vs[0][swz4(r0, gA + 8)]      = u0.h4[1];
        *(halfx4*)&Vs[0][swz4(r0 + 32, gA)]     = u1.h4[0];
        *(halfx4*)&Vs[0][swz4(r0 + 32, gA + 8)] = u1.h4[1];
    }
    __syncthreads();

    for (int t = 0; t < NT; ++t) {
        const int cur = t & 1;
        const bool more = (t + 1 < NT);
        if (more) {
            rK0 = *(const halfx8*)kp;
            rK1 = *(const halfx8*)(kp + 32 * H_);
            rV0 = *(const halfx8*)vp;
            rV1 = *(const halfx8*)(vp + 32 * T_);
            kp += 64 * H_; vp += 64;
        }

        // ---- S^T = K . Q^T : 2 s-tiles of 32, K-dim 64 = 4 chunks ----
        f32x16 sacc[2] = {};
        __builtin_amdgcn_s_setprio(1);
        #pragma unroll
        for (int st = 0; st < 2; ++st)
            #pragma unroll
            for (int kc = 0; kc < 4; ++kc) {
                halfx8 kf = *(const halfx8*)&Ks[cur][swz(st * 32 + lq, kc * 16 + hi * 8)];
                sacc[st] = __builtin_amdgcn_mfma_f32_32x32x16_f16(kf, qf[kc], sacc[st], 0, 0, 0);
            }
        __builtin_amdgcn_s_setprio(0);

        // ---- local max via max3 tree (no cross-lane on common path) ----
        float pm;
        {
            float a0 = max3f(sacc[0][0],  sacc[0][1],  sacc[0][2]);
            float a1 = max3f(sacc[0][3],  sacc[0][4],  sacc[0][5]);
            float a2 = max3f(sacc[0][6],  sacc[0][7],  sacc[0][8]);
            float a3 = max3f(sacc[0][9],  sacc[0][10], sacc[0][11]);
            float a4 = max3f(sacc[0][12], sacc[0][13], sacc[0][14]);
            float b0 = max3f(sacc[1][0],  sacc[1][1],  sacc[1][2]);
            float b1 = max3f(sacc[1][3],  sacc[1][4],  sacc[1][5]);
            float b2 = max3f(sacc[1][6],  sacc[1][7],  sacc[1][8]);
            float b3 = max3f(sacc[1][9],  sacc[1][10], sacc[1][11]);
            float b4 = max3f(sacc[1][12], sacc[1][13], sacc[1][14]);
            float c0 = max3f(a0, a1, sacc[0][15]);
            float c1 = max3f(a2, a3, a4);
            float c2 = max3f(b0, b1, sacc[1][15]);
            float c3 = max3f(b2, b3, b4);
            pm = fmaxf(max3f(c0, c1, c2), c3);
        }
        if (__any(pm > mr + 8.f)) {        // defer-max rescale (rare)
            pm = fmaxf(pm, __shfl_xor(pm, 32));
            float mnew  = fmaxf(mr, pm);
            float scale = fast_exp2(mr - mnew);
            mr = mnew; lr *= scale;
            #pragma unroll
            for (int dt = 0; dt < 2; ++dt)
                #pragma unroll
                for (int r = 0; r < 16; ++r) oacc[dt][r] *= scale;
        }
        // ---- exp + row-sum on VALU (4 partials for ILP) ----
        float p0 = 0.f, p1 = 0.f, p2 = 0.f, p3 = 0.f;
        #pragma unroll
        for (int st = 0; st < 2; ++st) {
            #pragma unroll
            for (int r = 0; r < 16; r += 4) {
                float e0 = fast_exp2(sacc[st][r + 0] - mr);
                float e1 = fast_exp2(sacc[st][r + 1] - mr);
                float e2 = fast_exp2(sacc[st][r + 2] - mr);
                float e3 = fast_exp2(sacc[st][r + 3] - mr);
                sacc[st][r + 0] = e0; sacc[st][r + 1] = e1;
                sacc[st][r + 2] = e2; sacc[st][r + 3] = e3;
                p0 += e0; p1 += e1; p2 += e2; p3 += e3;
            }
        }
        float ps = (p0 + p1) + (p2 + p3);
        lr += ps + __shfl_xor(ps, 32);

        // ---- P^T B-fragments: lane's OWN regs (sigma-permuted k-order) ----
        halfx8 pfrag[4];
        #pragma unroll
        for (int sc = 0; sc < 4; ++sc) {
            const int st = sc >> 1, rb = (sc & 1) * 8;
            i32x4 w;
            w[0] = pk2i(sacc[st][rb + 0], sacc[st][rb + 1]);
            w[1] = pk2i(sacc[st][rb + 2], sacc[st][rb + 3]);
            w[2] = pk2i(sacc[st][rb + 4], sacc[st][rb + 5]);
            w[3] = pk2i(sacc[st][rb + 6], sacc[st][rb + 7]);
            pfrag[sc] = __builtin_bit_cast(halfx8, w);
        }

        // ---- O^T += V^T . P^T ----
        __builtin_amdgcn_s_setprio(1);
        #pragma unroll
        for (int sc = 0; sc < 4; ++sc) {
            halfx8 vf0 = *(const halfx8*)&Vs[cur][swz(lq,      sc * 16 + hi * 8)];
            halfx8 vf1 = *(const halfx8*)&Vs[cur][swz(32 + lq, sc * 16 + hi * 8)];
            oacc[0] = __builtin_amdgcn_mfma_f32_32x32x16_f16(vf0, pfrag[sc], oacc[0], 0, 0, 0);
            oacc[1] = __builtin_amdgcn_mfma_f32_32x32x16_f16(vf1, pfrag[sc], oacc[1], 0, 0, 0);
        }
        __builtin_amdgcn_s_setprio(0);

        if (more) {
            const int nxt = cur ^ 1;
            *(halfx8*)&Ks[nxt][swz(r0, c8)]      = rK0;
            *(halfx8*)&Ks[nxt][swz(r0 + 32, c8)] = rK1;
            union { halfx8 h8; halfx4 h4[2]; } u0, u1;
            u0.h8 = rV0; u1.h8 = rV1;
            *(halfx4*)&Vs[nxt][swz4(r0, gA)]          = u0.h4[0];
            *(halfx4*)&Vs[nxt][swz4(r0, gA + 8)]      = u0.h4[1];
            *(halfx4*)&Vs[nxt][swz4(r0 + 32, gA)]     = u1.h4[0];
            *(halfx4*)&Vs[nxt][swz4(r0 + 32, gA + 8)] = u1.h4[1];
            __syncthreads();
        }
    }

    // ---- epilogue: normalized partial O (f16) + m,l ----
    const int BT = B_ * T_;
    const int grow = b * T_ + q0 + lq;
    float inv = 1.f / lr;
    half_t* od = Op + ((size_t)sp * BT + grow) * H_;
    #pragma unroll
    for (int dt = 0; dt < 2; ++dt)
        #pragma unroll
        for (int g = 0; g < 4; ++g) {
            union { halfx2 h2[2]; halfx4 h4; } u;
            u.h2[0] = pk2(oacc[dt][g * 4 + 0] * inv, oacc[dt][g * 4 + 1] * inv);
            u.h2[1] = pk2(oacc[dt][g * 4 + 2] * inv, oacc[dt][g * 4 + 3] * inv);
            *(halfx4*)(od + dt * 32 + g * 8 + hi * 4) = u.h4;
        }
    if (Mp != nullptr && hi == 0) {
        Mp[(size_t)sp * BT + grow] = mr;
        Lp[(size_t)sp * BT + grow] = lr;
    }
}

// ---------------------------------------------------------------------------
// Kernel 3: fused merge + out-projection.
// Stages merged O (softmax split-merge over NS partials, weights
// w_i = l_i * 2^(m_i - m*)) directly into LDS, then
// out = x + b_out + w_out[128,64] @ O^T.
// ---------------------------------------------------------------------------
__global__ __launch_bounds__(256) void outproj_kernel(
    const half_t* __restrict__ Op, const float* __restrict__ Mp,
    const float* __restrict__ Lp, int NS,
    const float* __restrict__ w_out, const float* __restrict__ b_out,
    const float* __restrict__ x, float* __restrict__ out)
{
    __shared__ __align__(16) half_t Ot[64][72];   // [t][h] (merged)

    const int tid  = threadIdx.x;
    const int lane = tid & 63;
    const int wave = tid >> 6;
    const int b    = blockIdx.x >> 6;
    const int t0   = (blockIdx.x & 63) << 6;

    const int rowA  = lane & 15;
    const int kgrp  = lane >> 4;
    const int row_d = kgrp << 2;
    const int BT    = B_ * T_;

    #pragma unroll
    for (int it = 0; it < 2; ++it) {
        int q = it * 256 + tid;
        int t = q >> 3, hc = (q & 7) * 8;
        const size_t row = (size_t)b * T_ + t0 + t;
        if (Mp == nullptr) {
            *(halfx8*)&Ot[t][hc] = *(const halfx8*)(Op + row * H_ + hc);
        } else {
            float m = Mp[row];
            for (int s = 1; s < NS; ++s) m = fmaxf(m, Mp[(size_t)s * BT + row]);
            float W = 0.f;
            float acc[8] = {};
            for (int s = 0; s < NS; ++s) {
                float w = Lp[(size_t)s * BT + row] *
                          __builtin_amdgcn_exp2f(Mp[(size_t)s * BT + row] - m);
                W += w;
                halfx8 o = *(const halfx8*)(Op + ((size_t)s * BT + row) * H_ + hc);
                #pragma unroll
                for (int j = 0; j < 8; ++j) acc[j] += w * (float)o[j];
            }
            float inv = 1.f / W;
            halfx8 r;
            #pragma unroll
            for (int j = 0; j < 8; ++j) r[j] = (half_t)(acc[j] * inv);
            *(halfx8*)&Ot[t][hc] = r;
        }
    }

    const int c0 = wave * 32;
    halfx8 wf[2][2];
    #pragma unroll
    for (int ct = 0; ct < 2; ++ct) {
        const float* wrow = w_out + (size_t)(c0 + ct * 16 + rowA) * H_;
        #pragma unroll
        for (int hc = 0; hc < 2; ++hc) {
            const float* p = wrow + hc * 32 + kgrp * 8;
            f32x4 a = *(const f32x4*)p;
            f32x4 c2 = *(const f32x4*)(p + 4);
            halfx8 f;
            f[0]=(half_t)a[0]; f[1]=(half_t)a[1]; f[2]=(half_t)a[2]; f[3]=(half_t)a[3];
            f[4]=(half_t)c2[0];f[5]=(half_t)c2[1];f[6]=(half_t)c2[2];f[7]=(half_t)c2[3];
            wf[ct][hc] = f;
        }
    }

    __syncthreads();

    #pragma unroll
    for (int ct = 0; ct < 2; ++ct) {
        #pragma unroll
        for (int tt = 0; tt < 4; ++tt) {
            f32x4 acc = {};
            #pragma unroll
            for (int hc = 0; hc < 2; ++hc) {
                halfx8 of = *(const halfx8*)&Ot[tt * 16 + rowA][hc * 32 + kgrp * 8];
                acc = __builtin_amdgcn_mfma_f32_16x16x32_f16(wf[ct][hc], of, acc, 0, 0, 0);
            }
            const int c = c0 + ct * 16 + row_d;
            const size_t base = (size_t)b * C_ * T_ + t0 + tt * 16 + rowA;
            #pragma unroll
            for (int r = 0; r < 4; ++r) {
                size_t idx = base + (size_t)(c + r) * T_;
                out[idx] = x[idx] + b_out[c + r] + acc[r];
            }
        }
    }
}

// ---------------------------------------------------------------------------
extern "C" void kernel_launch(void* const* d_in, const int* in_sizes, int n_in,
                              void* d_out, int out_size, void* d_ws, size_t ws_size,
                              hipStream_t stream) {
    const float* x       = (const float*)d_in[0];
    const float* w_theta = (const float*)d_in[1];
    const float* b_theta = (const float*)d_in[2];
    const float* w_phi   = (const float*)d_in[3];
    const float* b_phi   = (const float*)d_in[4];
    const float* w_g     = (const float*)d_in[5];
    const float* b_g     = (const float*)d_in[6];
    const float* w_out   = (const float*)d_in[7];
    const float* b_out   = (const float*)d_in[8];
    float* out = (float*)d_out;

    const size_t mat = (size_t)B_ * T_ * H_;   // 2 M elements
    const size_t BT  = (size_t)B_ * T_;        // 32768 rows
    half_t* Qw = (half_t*)d_ws;
    half_t* Kw = Qw + mat;
    half_t* Vw = Kw + mat;
    half_t* Ow = Vw + mat;                     // base: 16 MB
    const size_t base_b = 4 * mat * sizeof(half_t);

    auto need = [&](size_t ns) { return base_b + ns * mat * 2 + ns * BT * 8; };
    const int NS = (ws_size >= need(4)) ? 4 : ((ws_size >= need(2)) ? 2 : 1);

    half_t* Opart = Ow;
    float*  Mp = nullptr;
    float*  Lp = nullptr;
    if (NS > 1) {
        Opart = (half_t*)((char*)d_ws + base_b);
        Mp = (float*)((char*)d_ws + base_b + (size_t)NS * mat * 2);
        Lp = Mp + (size_t)NS * BT;
    }

    proj_kernel<<<dim3(B_ * (T_ / 64)), dim3(256), 0, stream>>>(
        x, w_theta, b_theta, w_phi, b_phi, w_g, b_g, Qw, Kw, Vw);
    attn_kernel<<<dim3(B_ * (T_ / 128) * NS), dim3(256), 0, stream>>>(
        Qw, Kw, Vw, Opart, Mp, Lp, NS);
    outproj_kernel<<<dim3(B_ * (T_ / 64)), dim3(256), 0, stream>>>(
        Opart, Mp, Lp, NS, w_out, b_out, x, out);
}